// Round 1
// baseline (8752.279 us; speedup 1.0000x reference)
//
#include <hip/hip_runtime.h>
#include <math.h>

#define Hd 300
#define Ld 64
#define TM 16     // graphs per block
#define TMH 8     // graphs per half-block
#define NTH 640   // 2 halves x 320 threads (300 active channels each)

// ws layout (floats): WTf [150*900*4], WTb [150*900*4]   (~4.3 MB total)
// WT layout: [kk][row r][q] with kk in [0,150), r in [0,900), q in [0,4):
//   k = 2*kk + (q>>1); q&1==0 -> W_ih[r][k], q&1==1 -> W_hh[r][k]
// so one float4 at (kk, r) = (Wih[r][2kk], Whh[r][2kk], Wih[r][2kk+1], Whh[r][2kk+1])

__global__ void k_prep_w(const float* __restrict__ Wih_f, const float* __restrict__ Whh_f,
                         const float* __restrict__ Wih_b, const float* __restrict__ Whh_b,
                         const float* __restrict__ node, const float* __restrict__ bias,
                         float* __restrict__ WTf, float* __restrict__ WTb,
                         float* __restrict__ out) {
  int e = blockIdx.x * blockDim.x + threadIdx.x;
  if (e < Hd) {
    // head row: out[0] = [message[0], message[0]]
    float mv = fmaxf(node[e] + bias[e], 0.f);
    out[e] = mv;
    out[Hd + e] = mv;
  }
  if (e >= 2 * 540000) return;
  int dir = e >= 540000;
  int e2 = e - dir * 540000;
  int kk = e2 / 3600;
  int rem = e2 - kk * 3600;
  int r = rem >> 2;
  int q = rem & 3;
  int k = 2 * kk + (q >> 1);
  const float* Wih = dir ? Wih_b : Wih_f;
  const float* Whh = dir ? Whh_b : Whh_f;
  float v = (q & 1) ? Whh[r * Hd + k] : Wih[r * Hd + k];
  (dir ? WTb : WTf)[e2] = v;
}

__global__ __launch_bounds__(NTH) void k_gru(
    const float* __restrict__ node, const float* __restrict__ bias,
    const float* __restrict__ WTf, const float* __restrict__ WTb,
    const float* __restrict__ bih_f, const float* __restrict__ bhh_f,
    const float* __restrict__ bih_b, const float* __restrict__ bhh_b,
    const int* __restrict__ starts, const int* __restrict__ sizes,
    float* __restrict__ out, int ntiles) {
  __shared__ float xt[TM][Hd];   // staged x (relu(node+bias) or 0) for current step
  __shared__ float hl[TM][Hd];   // hidden state, lives here across all 64 steps
  __shared__ int sst[TM], ssz[TM];

  int bid = blockIdx.x;
  int dir = bid >= ntiles;
  int g0 = (bid - dir * ntiles) * TM;
  int tid = threadIdx.x;

  if (tid < TM) {
    sst[tid] = starts[g0 + tid];
    ssz[tid] = sizes[g0 + tid];
  }
  __syncthreads();

  const float* WT  = dir ? WTb   : WTf;
  const float* bih = dir ? bih_b : bih_f;
  const float* bhh = dir ? bhh_b : bhh_f;

  int half = tid / 320;          // waves 0-4 = half 0, waves 5-9 = half 1
  int lt = tid - half * 320;
  int c = lt;                    // channel
  bool act = lt < Hd;
  int mbase = half * TMH;

  float br = 0.f, bz = 0.f, bnx = 0.f, bnh = 0.f;
  if (act) {
    br  = bih[c] + bhh[c];
    bz  = bih[Hd + c] + bhh[Hd + c];
    bnx = bih[2 * Hd + c];
    bnh = bhh[2 * Hd + c];
  }

  // h0 = per-graph max-pool of RAW node over valid rows
  if (act) {
    for (int ml = 0; ml < TMH; ++ml) {
      int m = mbase + ml;
      int st = sst[m], sz = ssz[m];
      float hv = -INFINITY;
      for (int i = 0; i < sz; ++i)
        hv = fmaxf(hv, node[(size_t)(st + i) * Hd + c]);
      hl[m][c] = hv;
    }
  }

  for (int t = 0; t < Ld; ++t) {
    int time = dir ? (Ld - 1 - t) : t;

    // stage x tile: relu(node+bias) for valid rows, 0 for padding
    for (int i = tid; i < TM * Hd; i += NTH) {
      int m = i / Hd;
      int k = i - m * Hd;
      int st = sst[m], sz = ssz[m];
      float v = 0.f;
      if (time < sz) v = fmaxf(node[(size_t)(st + time) * Hd + k] + bias[k], 0.f);
      xt[m][k] = v;
    }
    __syncthreads();  // xt staged, hl (init or prev update) visible

    float hn[TMH];
    if (act) {
      float a0[TMH], a1[TMH], a2[TMH], a3[TMH];  // r, z, i_n, h_n accumulators
#pragma unroll
      for (int ml = 0; ml < TMH; ++ml) { a0[ml] = 0.f; a1[ml] = 0.f; a2[ml] = 0.f; a3[ml] = 0.f; }

#pragma unroll 2
      for (int j = 0; j < 75; ++j) {  // 4 k's per iter (k = 4j..4j+3)
        const float4 w0r = *(const float4*)&WT[((2 * j) * 900 + c) * 4];
        const float4 w0z = *(const float4*)&WT[((2 * j) * 900 + Hd + c) * 4];
        const float4 w0n = *(const float4*)&WT[((2 * j) * 900 + 2 * Hd + c) * 4];
        const float4 w1r = *(const float4*)&WT[((2 * j + 1) * 900 + c) * 4];
        const float4 w1z = *(const float4*)&WT[((2 * j + 1) * 900 + Hd + c) * 4];
        const float4 w1n = *(const float4*)&WT[((2 * j + 1) * 900 + 2 * Hd + c) * 4];
#pragma unroll
        for (int ml = 0; ml < TMH; ++ml) {
          int m = mbase + ml;
          float4 x4 = *(const float4*)&xt[m][4 * j];
          float4 h4 = *(const float4*)&hl[m][4 * j];
          a0[ml] += w0r.x * x4.x + w0r.y * h4.x + w0r.z * x4.y + w0r.w * h4.y
                  + w1r.x * x4.z + w1r.y * h4.z + w1r.z * x4.w + w1r.w * h4.w;
          a1[ml] += w0z.x * x4.x + w0z.y * h4.x + w0z.z * x4.y + w0z.w * h4.y
                  + w1z.x * x4.z + w1z.y * h4.z + w1z.z * x4.w + w1z.w * h4.w;
          a2[ml] += w0n.x * x4.x + w0n.z * x4.y + w1n.x * x4.z + w1n.z * x4.w;
          a3[ml] += w0n.y * h4.x + w0n.w * h4.y + w1n.y * h4.z + w1n.w * h4.w;
        }
      }

#pragma unroll
      for (int ml = 0; ml < TMH; ++ml) {
        int m = mbase + ml;
        float r = 1.f / (1.f + __expf(-(a0[ml] + br)));
        float z = 1.f / (1.f + __expf(-(a1[ml] + bz)));
        float n = tanhf(a2[ml] + bnx + r * (a3[ml] + bnh));
        hn[ml] = (1.f - z) * n + z * hl[m][c];
      }
      // write valid outputs: row 1 + start + time, cols [dir*300, dir*300+300)
      for (int ml = 0; ml < TMH; ++ml) {
        int m = mbase + ml;
        if (time < ssz[m])
          out[(size_t)(1 + sst[m] + time) * 600 + dir * Hd + c] = hn[ml];
      }
    }
    __syncthreads();  // all GEMM readers done before hl/xt are overwritten
    if (act) {
#pragma unroll
      for (int ml = 0; ml < TMH; ++ml) hl[mbase + ml][c] = hn[ml];
    }
  }
}

extern "C" void kernel_launch(void* const* d_in, const int* in_sizes, int n_in,
                              void* d_out, int out_size, void* d_ws, size_t ws_size,
                              hipStream_t stream) {
  const float* node  = (const float*)d_in[0];
  const float* bias  = (const float*)d_in[1];
  const float* Wih_f = (const float*)d_in[2];
  const float* Whh_f = (const float*)d_in[3];
  const float* bih_f = (const float*)d_in[4];
  const float* bhh_f = (const float*)d_in[5];
  const float* Wih_b = (const float*)d_in[6];
  const float* Whh_b = (const float*)d_in[7];
  const float* bih_b = (const float*)d_in[8];
  const float* bhh_b = (const float*)d_in[9];
  const int* starts  = (const int*)d_in[10];
  const int* sizes   = (const int*)d_in[11];

  int ngr = in_sizes[10];          // 2048 graphs
  int ntiles = ngr / TM;           // 128

  float* out = (float*)d_out;
  float* WTf = (float*)d_ws;
  float* WTb = WTf + 540000;

  hipLaunchKernelGGL(k_prep_w, dim3((2 * 540000 + 255) / 256), dim3(256), 0, stream,
                     Wih_f, Whh_f, Wih_b, Whh_b, node, bias, WTf, WTb, out);
  hipLaunchKernelGGL(k_gru, dim3(2 * ntiles), dim3(NTH), 0, stream,
                     node, bias, WTf, WTb, bih_f, bhh_f, bih_b, bhh_b,
                     starts, sizes, out, ntiles);
}

// Round 2
// 3678.897 us; speedup vs baseline: 2.3790x; 2.3790x over previous
//
#include <hip/hip_runtime.h>
#include <math.h>

#define Hc 300
#define Hp 304
#define Ld 64
#define Gb 32
#define NT 57
#define KT 10
#define SPD (2*2*KT*NT*64)   // f16x8 fragment slots per direction = 145920

typedef _Float16 f16x8 __attribute__((ext_vector_type(8)));
typedef float f32x4 __attribute__((ext_vector_type(4)));

#define MFMA16(a,b,c) __builtin_amdgcn_mfma_f32_16x16x32_f16(a,b,c,0,0,0)

// ---------------- prep: weight fragments (fp16 hi/lo), combined biases, head row ----------------
// B fragment layout per dir: [gemm(x=0,h=1)][term(hi=0,lo=1)][kt][nt][lane] -> 8 halfs
// frag content: B[k][n] with k = kt*32 + (lane>>4)*8 + e, n = nt*16 + (lane&15)
// n -> group g = n/304, c = n%304 ; W row = g*300+c ; zero if c>=300 or k>=300
__global__ __launch_bounds__(256) void k_prep(
    const float* __restrict__ Wih_f, const float* __restrict__ Whh_f,
    const float* __restrict__ Wih_b, const float* __restrict__ Whh_b,
    const float* __restrict__ bih_f, const float* __restrict__ bhh_f,
    const float* __restrict__ bih_b, const float* __restrict__ bhh_b,
    const float* __restrict__ node, const float* __restrict__ bias,
    f16x8* __restrict__ Bfrag, float* __restrict__ bcomb, float* __restrict__ out)
{
  int gid = blockIdx.x*256 + threadIdx.x;
  const int TOTF = 2*SPD;
  if (gid < TOTF) {
    int lane = gid & 63;
    int s = gid >> 6;
    int nt = s % NT;  s /= NT;
    int kt = s % KT;  s /= KT;
    int term = s & 1; s >>= 1;
    int gemm = s & 1; s >>= 1;
    int dir  = s;
    int n = nt*16 + (lane & 15);
    int grp = n / Hp, c = n - grp*Hp;
    int row = grp*Hc + c;
    const float* W = dir ? (gemm ? Whh_b : Wih_b) : (gemm ? Whh_f : Wih_f);
    f16x8 v;
#pragma unroll
    for (int e = 0; e < 8; ++e) {
      int k = kt*32 + (lane>>4)*8 + e;
      float w = (c < Hc && k < Hc) ? W[row*Hc + k] : 0.f;
      _Float16 hi = (_Float16)w;
      v[e] = term ? (_Float16)(w - (float)hi) : hi;
    }
    Bfrag[gid] = v;
    return;
  }
  int i = gid - TOTF;
  if (i < 2432) {   // bcomb: [dir][4][Hp] : r-bias, z-bias, i_n bias, h_n bias
    int dir = i / 1216; int r = i - dir*1216;
    int buf = r / Hp, c = r - buf*Hp;
    const float* bih = dir ? bih_b : bih_f;
    const float* bhh = dir ? bhh_b : bhh_f;
    float v = 0.f;
    if (c < Hc) {
      if (buf == 0) v = bih[c] + bhh[c];
      else if (buf == 1) v = bih[Hc+c] + bhh[Hc+c];
      else if (buf == 2) v = bih[2*Hc+c];
      else v = bhh[2*Hc+c];
    }
    bcomb[i] = v;
    return;
  }
  i -= 2432;
  if (i < 600) {    // head row: out[0] = [message[0], message[0]]
    int c = (i < Hc) ? i : i - Hc;
    out[i] = fmaxf(node[c] + bias[c], 0.f);
  }
}

// ---------------- recurrent kernel helpers ----------------
// owner threads: chunk cid in [0,608): gl = cid/38 (graph local in pass), c8 = cid%38 (8-channel chunk)
template<int P>
__device__ __forceinline__ void h0init(
    float (&hreg)[2][2][8], _Float16 (&AfH)[2][2][KT][512],
    const int* sst, const int* ssz, const float* __restrict__ node, int tid)
{
#pragma unroll
  for (int sl = 0; sl < 2; ++sl) {
    int cid = tid + sl*512;
    if (cid < 608) {
      int gl = cid / 38, c8 = cid - gl*38;
      int g = P*16 + gl;
      int stg = sst[g], szg = ssz[g];
      float hv[8];
#pragma unroll
      for (int e = 0; e < 8; ++e) hv[e] = -INFINITY;
      for (int i = 0; i < szg; ++i) {
        const float* rp = &node[(size_t)(stg+i)*Hc + c8*8];
        f32x4 a0 = *(const f32x4*)rp;
#pragma unroll
        for (int e = 0; e < 4; ++e) hv[e] = fmaxf(hv[e], a0[e]);
        if (c8 < 37) {
          f32x4 a1 = *(const f32x4*)(rp+4);
#pragma unroll
          for (int e = 0; e < 4; ++e) hv[e+4] = fmaxf(hv[e+4], a1[e]);
        }
      }
      if (c8 == 37) { hv[4]=0.f; hv[5]=0.f; hv[6]=0.f; hv[7]=0.f; }
      f16x8 fh, fl;
#pragma unroll
      for (int e = 0; e < 8; ++e) {
        hreg[P][sl][e] = hv[e];
        fh[e] = (_Float16)hv[e];
        fl[e] = (_Float16)(hv[e] - (float)fh[e]);
      }
      *(f16x8*)&AfH[0][P][c8>>2][((c8&3)*16 + gl)*8] = fh;
      *(f16x8*)&AfH[1][P][c8>>2][((c8&3)*16 + gl)*8] = fl;
    }
  }
}

template<int P>
__device__ __forceinline__ void epilogue(
    float (&hreg)[2][2][8], float (&Db)[4][16][Hp], _Float16 (&AfH)[2][2][KT][512],
    const int* sst, const int* ssz, const float* __restrict__ bc,
    float* __restrict__ out, int dir, int time, int tid)
{
#pragma unroll
  for (int sl = 0; sl < 2; ++sl) {
    int cid = tid + sl*512;
    if (cid < 608) {
      int gl = cid / 38, c8 = cid - gl*38;
      int g = P*16 + gl;
      f32x4 dr0 = *(const f32x4*)&Db[0][gl][c8*8];
      f32x4 dr1 = *(const f32x4*)&Db[0][gl][c8*8+4];
      f32x4 dz0 = *(const f32x4*)&Db[1][gl][c8*8];
      f32x4 dz1 = *(const f32x4*)&Db[1][gl][c8*8+4];
      f32x4 di0 = *(const f32x4*)&Db[2][gl][c8*8];
      f32x4 di1 = *(const f32x4*)&Db[2][gl][c8*8+4];
      f32x4 dh0 = *(const f32x4*)&Db[3][gl][c8*8];
      f32x4 dh1 = *(const f32x4*)&Db[3][gl][c8*8+4];
      f32x4 br0 = *(const f32x4*)&bc[0*Hp + c8*8];
      f32x4 br1 = *(const f32x4*)&bc[0*Hp + c8*8+4];
      f32x4 bz0 = *(const f32x4*)&bc[1*Hp + c8*8];
      f32x4 bz1 = *(const f32x4*)&bc[1*Hp + c8*8+4];
      f32x4 bi0 = *(const f32x4*)&bc[2*Hp + c8*8];
      f32x4 bi1 = *(const f32x4*)&bc[2*Hp + c8*8+4];
      f32x4 bh0 = *(const f32x4*)&bc[3*Hp + c8*8];
      f32x4 bh1 = *(const f32x4*)&bc[3*Hp + c8*8+4];
      float hn[8];
#pragma unroll
      for (int e = 0; e < 8; ++e) {
        float drv = (e<4) ? dr0[e] : dr1[e-4];
        float dzv = (e<4) ? dz0[e] : dz1[e-4];
        float div_ = (e<4) ? di0[e] : di1[e-4];
        float dhv = (e<4) ? dh0[e] : dh1[e-4];
        float brv = (e<4) ? br0[e] : br1[e-4];
        float bzv = (e<4) ? bz0[e] : bz1[e-4];
        float biv = (e<4) ? bi0[e] : bi1[e-4];
        float bhv = (e<4) ? bh0[e] : bh1[e-4];
        float rr = 1.f/(1.f + __expf(-(drv + brv)));
        float zz = 1.f/(1.f + __expf(-(dzv + bzv)));
        float nn = tanhf(div_ + biv + rr*(dhv + bhv));
        float hv = (1.f - zz)*nn + zz*hreg[P][sl][e];
        if (c8 == 37 && e >= 4) hv = 0.f;
        hreg[P][sl][e] = hv;
        hn[e] = hv;
      }
      int stg = sst[g], szg = ssz[g];
      if (time < szg) {
        size_t ro = (size_t)(1 + stg + time)*600 + dir*Hc + c8*8;
        f32x4 o0 = {hn[0],hn[1],hn[2],hn[3]};
        *(f32x4*)&out[ro] = o0;
        if (c8 < 37) { f32x4 o1 = {hn[4],hn[5],hn[6],hn[7]}; *(f32x4*)&out[ro+4] = o1; }
      }
      f16x8 fh, fl;
#pragma unroll
      for (int e = 0; e < 8; ++e) {
        fh[e] = (_Float16)hn[e];
        fl[e] = (_Float16)(hn[e] - (float)fh[e]);
      }
      *(f16x8*)&AfH[0][P][c8>>2][((c8&3)*16 + gl)*8] = fh;
      *(f16x8*)&AfH[1][P][c8>>2][((c8&3)*16 + gl)*8] = fl;
    }
  }
}

// MFMA chunk: CH is a literal (0/1); covers nt = wv + 8*(CH*4+sl)
#define CHUNK_MFMA(CH) \
  { _Pragma("unroll 1") \
    for (int kt = 0; kt < KT; ++kt) { \
      int k8 = kt*32 + l4*8; \
      f32x4 bb0 = z4, bb1 = z4; \
      if (k8 < Hc)   bb0 = *(const f32x4*)&bias[k8]; \
      if (k8+4 < Hc) bb1 = *(const f32x4*)&bias[k8+4]; \
      f32x4 xA0 = z4, xA1 = z4, xB0 = z4, xB1 = z4; \
      if (vA && k8 < Hc)   xA0 = *(const f32x4*)&node[(size_t)(stA+time)*Hc + k8]; \
      if (vA && k8+4 < Hc) xA1 = *(const f32x4*)&node[(size_t)(stA+time)*Hc + k8+4]; \
      if (vB && k8 < Hc)   xB0 = *(const f32x4*)&node[(size_t)(stB+time)*Hc + k8]; \
      if (vB && k8+4 < Hc) xB1 = *(const f32x4*)&node[(size_t)(stB+time)*Hc + k8+4]; \
      f16x8 xh0, xl0, xh1, xl1; \
      _Pragma("unroll") \
      for (int e = 0; e < 4; ++e) { \
        float va = vA ? fmaxf(xA0[e]+bb0[e], 0.f) : 0.f; \
        xh0[e] = (_Float16)va; xl0[e] = (_Float16)(va - (float)xh0[e]); \
        float vb = vA ? fmaxf(xA1[e]+bb1[e], 0.f) : 0.f; \
        xh0[e+4] = (_Float16)vb; xl0[e+4] = (_Float16)(vb - (float)xh0[e+4]); \
        float vc = vB ? fmaxf(xB0[e]+bb0[e], 0.f) : 0.f; \
        xh1[e] = (_Float16)vc; xl1[e] = (_Float16)(vc - (float)xh1[e]); \
        float vd = vB ? fmaxf(xB1[e]+bb1[e], 0.f) : 0.f; \
        xh1[e+4] = (_Float16)vd; xl1[e+4] = (_Float16)(vd - (float)xh1[e+4]); \
      } \
      f16x8 hh0 = *(const f16x8*)&AfH[0][0][kt][lane*8]; \
      f16x8 hl0 = *(const f16x8*)&AfH[1][0][kt][lane*8]; \
      f16x8 hh1 = *(const f16x8*)&AfH[0][1][kt][lane*8]; \
      f16x8 hl1 = *(const f16x8*)&AfH[1][1][kt][lane*8]; \
      _Pragma("unroll") \
      for (int sl = 0; sl < 4; ++sl) { \
        int ntv = wv + 8*((CH)*4+sl); \
        if (ntv < NT) { \
          const f16x8* bp = Bd + (kt*NT + ntv)*64 + lane; \
          f16x8 bxh = bp[0]; \
          f16x8 bxl = bp[KT*NT*64]; \
          f16x8 bhh = bp[2*KT*NT*64]; \
          f16x8 bhl = bp[3*KT*NT*64]; \
          aA[CH][sl][0] = MFMA16(xh0, bxh, aA[CH][sl][0]); \
          aA[CH][sl][0] = MFMA16(xh0, bxl, aA[CH][sl][0]); \
          aA[CH][sl][0] = MFMA16(xl0, bxh, aA[CH][sl][0]); \
          aA[CH][sl][1] = MFMA16(xh1, bxh, aA[CH][sl][1]); \
          aA[CH][sl][1] = MFMA16(xh1, bxl, aA[CH][sl][1]); \
          aA[CH][sl][1] = MFMA16(xl1, bxh, aA[CH][sl][1]); \
          if (ntv < 38) { \
            aA[CH][sl][0] = MFMA16(hh0, bhh, aA[CH][sl][0]); \
            aA[CH][sl][0] = MFMA16(hh0, bhl, aA[CH][sl][0]); \
            aA[CH][sl][0] = MFMA16(hl0, bhh, aA[CH][sl][0]); \
            aA[CH][sl][1] = MFMA16(hh1, bhh, aA[CH][sl][1]); \
            aA[CH][sl][1] = MFMA16(hh1, bhl, aA[CH][sl][1]); \
            aA[CH][sl][1] = MFMA16(hl1, bhh, aA[CH][sl][1]); \
          } else { \
            aB[CH][sl][0] = MFMA16(hh0, bhh, aB[CH][sl][0]); \
            aB[CH][sl][0] = MFMA16(hh0, bhl, aB[CH][sl][0]); \
            aB[CH][sl][0] = MFMA16(hl0, bhh, aB[CH][sl][0]); \
            aB[CH][sl][1] = MFMA16(hh1, bhh, aB[CH][sl][1]); \
            aB[CH][sl][1] = MFMA16(hh1, bhl, aB[CH][sl][1]); \
            aB[CH][sl][1] = MFMA16(hl1, bhh, aB[CH][sl][1]); \
          } \
        } \
      } \
    } }

#define DBW(CH, MT) \
  { _Pragma("unroll") \
    for (int sl = 0; sl < 4; ++sl) { \
      int ntv = wv + 8*((CH)*4+sl); \
      if (ntv < NT) { \
        int grp = ntv/19; int col = (ntv - grp*19)*16 + l15; \
        _Pragma("unroll") \
        for (int j = 0; j < 4; ++j) { \
          int rw = l4*4 + j; \
          float va = aA[CH][sl][MT][j]; \
          if (grp == 0) Db[0][rw][col] = va; \
          else if (grp == 1) Db[1][rw][col] = va; \
          else { Db[2][rw][col] = va; Db[3][rw][col] = aB[CH][sl][MT][j]; } \
        } \
      } \
    } }

__global__ __launch_bounds__(512, 2) void k_rec(
    const float* __restrict__ node, const float* __restrict__ bias,
    const f16x8* __restrict__ Bfrag, const float* __restrict__ bcomb,
    const int* __restrict__ starts, const int* __restrict__ sizes,
    float* __restrict__ out, int ntile)
{
  __shared__ __align__(16) _Float16 AfH[2][2][KT][512];  // [term][mt][kt][lane*8] h-fragments
  __shared__ __align__(16) float Db[4][16][Hp];          // r, z, i_n, h_n pre-acts (one 16-graph pass)
  __shared__ int sst[Gb], ssz[Gb];

  int bid = blockIdx.x;
  int xcd = bid & 7, bslot = bid >> 3;
  int dir = (xcd >= 4) ? 1 : 0;                          // cluster one direction per XCD (L2 locality)
  int tile = (xcd & 3)*(ntile >> 2) + bslot;

  int tid = threadIdx.x;
  int wv = tid >> 6, lane = tid & 63;
  int l15 = lane & 15, l4 = lane >> 4;

  if (tid < Gb) {
    sst[tid] = starts[tile*Gb + tid];
    ssz[tid] = sizes[tile*Gb + tid];
  }
  __syncthreads();

  const f16x8* Bd = Bfrag + (size_t)dir * SPD;
  const float* bc = bcomb + dir*1216;
  const f32x4 z4 = {0.f, 0.f, 0.f, 0.f};
  float hreg[2][2][8];

  h0init<0>(hreg, AfH, sst, ssz, node, tid);
  h0init<1>(hreg, AfH, sst, ssz, node, tid);

  int gA = l15, gB2 = 16 + l15;
  int stA = sst[gA], szA = ssz[gA];
  int stB = sst[gB2], szB = ssz[gB2];

  for (int t = 0; t < Ld; ++t) {
    int time = dir ? (Ld-1-t) : t;
    __syncthreads();                      // S1: AfH (h0 or previous epilogue) visible; Db free
    bool vA = time < szA, vB = time < szB;
    f32x4 aA[2][4][2], aB[2][4][2];
#pragma unroll
    for (int c = 0; c < 2; ++c)
#pragma unroll
      for (int s = 0; s < 4; ++s)
#pragma unroll
        for (int m = 0; m < 2; ++m) { aA[c][s][m] = z4; aB[c][s][m] = z4; }

    CHUNK_MFMA(0)
    DBW(0, 0)
    CHUNK_MFMA(1)
    DBW(1, 0)
    __syncthreads();                      // S2: Db pass0 complete
    epilogue<0>(hreg, Db, AfH, sst, ssz, bc, out, dir, time, tid);
    __syncthreads();                      // S3: pass0 reads done
    DBW(0, 1)
    DBW(1, 1)
    __syncthreads();                      // S4: Db pass1 complete
    epilogue<1>(hreg, Db, AfH, sst, ssz, bc, out, dir, time, tid);
  }
}

extern "C" void kernel_launch(void* const* d_in, const int* in_sizes, int n_in,
                              void* d_out, int out_size, void* d_ws, size_t ws_size,
                              hipStream_t stream) {
  const float* node  = (const float*)d_in[0];
  const float* bias  = (const float*)d_in[1];
  const float* Wih_f = (const float*)d_in[2];
  const float* Whh_f = (const float*)d_in[3];
  const float* bih_f = (const float*)d_in[4];
  const float* bhh_f = (const float*)d_in[5];
  const float* Wih_b = (const float*)d_in[6];
  const float* Whh_b = (const float*)d_in[7];
  const float* bih_b = (const float*)d_in[8];
  const float* bhh_b = (const float*)d_in[9];
  const int* starts  = (const int*)d_in[10];
  const int* sizes   = (const int*)d_in[11];

  int ngr = in_sizes[10];          // 2048 graphs
  int ntile = ngr / Gb;            // 64 tiles of 32 graphs

  float* out = (float*)d_out;
  f16x8* Bfrag = (f16x8*)d_ws;
  float* bcomb = (float*)((char*)d_ws + (size_t)2*SPD*16);

  // prep: 2*SPD frag slots + 2432 bcomb + 600 head = 294,872 threads
  k_prep<<<dim3(1152), dim3(256), 0, stream>>>(
      Wih_f, Whh_f, Wih_b, Whh_b, bih_f, bhh_f, bih_b, bhh_b,
      node, bias, Bfrag, bcomb, out);
  k_rec<<<dim3(2*ntile), dim3(512), 0, stream>>>(
      node, bias, Bfrag, bcomb, starts, sizes, out, ntile);
}

// Round 3
// 1884.208 us; speedup vs baseline: 4.6451x; 1.9525x over previous
//
#include <hip/hip_runtime.h>
#include <math.h>

#define Hc 300
#define Ld 64
#define GB 16        // graphs per block
#define KT 10        // K tiles of 32 (K padded 300->320)
#define NQ 20        // 16-col q-groups per gate section (N padded 300->320)
#define NT 60        // total n-tiles = 3 sections * NQ
#define PERDIR (2*2*KT*NT*64)   // f16x8 frags per dir = 153600
#define TOTF   (2*PERDIR)       // 307200 total

typedef _Float16 f16x8 __attribute__((ext_vector_type(8)));
typedef float f32x4 __attribute__((ext_vector_type(4)));
typedef unsigned int u32;

#define MFMA16(a,b,c) __builtin_amdgcn_mfma_f32_16x16x32_f16(a,b,c,0,0,0)

// ---------------------------------------------------------------------------
// prep: weight fragments (fp16 hi/lo), combined biases, head output row
// B frag layout: [dir][gemm x/h][term hi/lo][kt][nt][lane] -> f16x8
//   nt = sec*NQ + q ; col channel c = q*16 + (lane&15) ; W row = sec*300 + c
//   k = kt*32 + (lane>>4)*8 + e ; zero if c>=300 or k>=300
// bcomb: [dir][4][320] = r-bias(ih+hh), z-bias(ih+hh), n-ih-bias, n-hh-bias
// ---------------------------------------------------------------------------
__global__ __launch_bounds__(256) void k_prep(
    const float* __restrict__ Wih_f, const float* __restrict__ Whh_f,
    const float* __restrict__ Wih_b, const float* __restrict__ Whh_b,
    const float* __restrict__ bih_f, const float* __restrict__ bhh_f,
    const float* __restrict__ bih_b, const float* __restrict__ bhh_b,
    const float* __restrict__ node, const float* __restrict__ bias,
    f16x8* __restrict__ Bfrag, float* __restrict__ bcomb, float* __restrict__ out)
{
  int gid = blockIdx.x*256 + threadIdx.x;
  if (gid < TOTF) {
    int lane = gid & 63;
    int s = gid >> 6;
    int nt = s % NT;  s /= NT;
    int kt = s % KT;  s /= KT;
    int term = s & 1; s >>= 1;
    int gemm = s & 1; s >>= 1;
    int dir  = s;
    int sec = nt / NQ, qq = nt - sec*NQ;
    int c = qq*16 + (lane & 15);
    int row = sec*Hc + c;
    const float* W = dir ? (gemm ? Whh_b : Wih_b) : (gemm ? Whh_f : Wih_f);
    f16x8 v;
#pragma unroll
    for (int e = 0; e < 8; ++e) {
      int k = kt*32 + (lane>>4)*8 + e;
      float wv = (c < Hc && k < Hc) ? W[row*Hc + k] : 0.f;
      _Float16 hi = (_Float16)wv;
      v[e] = term ? (_Float16)(wv - (float)hi) : hi;
    }
    Bfrag[gid] = v;
    return;
  }
  int i = gid - TOTF;
  if (i < 2560) {
    int dir = i / 1280; int r = i - dir*1280;
    int buf = r / 320, c = r - buf*320;
    const float* bih = dir ? bih_b : bih_f;
    const float* bhh = dir ? bhh_b : bhh_f;
    float v = 0.f;
    if (c < Hc) {
      if (buf == 0) v = bih[c] + bhh[c];
      else if (buf == 1) v = bih[Hc+c] + bhh[Hc+c];
      else if (buf == 2) v = bih[2*Hc+c];
      else v = bhh[2*Hc+c];
    }
    bcomb[i] = v;
    return;
  }
  i -= 2560;
  if (i < 600) {   // head row: out[0] = [message[0], message[0]]
    int c = (i < Hc) ? i : i - Hc;
    out[i] = fmaxf(node[c] + bias[c], 0.f);
  }
}

// ---------------------------------------------------------------------------
// recurrent kernel
// ---------------------------------------------------------------------------
__device__ __forceinline__ u32 f32_to_hl(float v) {
  union { _Float16 f; unsigned short u; } a, b;
  a.f = (_Float16)v;
  b.f = (_Float16)(v - (float)a.f);
  return (u32)a.u | ((u32)b.u << 16);
}

// write h value (channel pair cE..cE+1, graph g) into A-fragment layout:
// half index = ((((cE>>3)&3)*16 + g)*8 + (cE&7)) within [term][kt] slot.
// even lane holds even channel: lanes pair-exchange packed (hi,lo) via bpermute;
// even lane stores the hi-term dword, odd lane stores the lo-term dword.
__device__ __forceinline__ void afh_write(u32 (&buf)[2][KT][256],
                                          int l15, int g, int cE, u32 p, int lane) {
  u32 qv = (u32)__builtin_amdgcn_ds_bpermute((lane ^ 1) << 2, (int)p);
  int kt = cE >> 5;
  int dw = ((((cE >> 3) & 3) << 4) + g) * 4 + ((cE & 7) >> 1);
  if ((l15 & 1) == 0) buf[0][kt][dw] = (p & 0xFFFFu) | (qv << 16);
  else                buf[1][kt][dw] = (qv >> 16) | (p & 0xFFFF0000u);
}

__global__ __launch_bounds__(640) void k_rec(
    const float* __restrict__ node, const float* __restrict__ bias,
    const f16x8* __restrict__ Bfrag, const float* __restrict__ bcomb,
    const int* __restrict__ starts, const int* __restrict__ sizes,
    float* __restrict__ out)
{
  __shared__ __align__(16) u32 AfX[2][4][KT][256];  // [term][mt][kt][dword] x-fragments
  __shared__ __align__(16) u32 AfH[2][2][KT][256];  // [buf][term][kt][dword] h-fragments
  __shared__ int sst[GB], ssz[GB];

  int bid = blockIdx.x;
  int dir = (bid & 7) >= 4;                  // XCDs 0-3: forward, 4-7: backward
  int tslot = (bid & 3) + (bid >> 3) * 4;    // bijective tile id per dir
  int g0 = tslot * GB;

  int tid = threadIdx.x;
  int w = tid >> 6, lane = tid & 63;
  int l15 = lane & 15, l4 = lane >> 4;

  if (tid < GB) { sst[tid] = starts[g0 + tid]; ssz[tid] = sizes[g0 + tid]; }
  __syncthreads();

  int qv[2] = { w, w + 10 };
  int cq[2] = { qv[0]*16 + l15, qv[1]*16 + l15 };

  const float* bc = bcomb + dir*1280;
  float bcr[2], bcz[2], bci[2], bch[2];
#pragma unroll
  for (int qi = 0; qi < 2; ++qi) {
    int c = cq[qi];
    bcr[qi] = bc[c]; bcz[qi] = bc[320 + c]; bci[qi] = bc[640 + c]; bch[qi] = bc[960 + c];
  }
  int stj[4], szj[4];
#pragma unroll
  for (int j = 0; j < 4; ++j) { stj[j] = sst[(l4<<2)+j]; szj[j] = ssz[(l4<<2)+j]; }
  int stG = sst[l15], szG = ssz[l15];       // graph for x-staging (row = l15)

  const f16x8* Bd  = Bfrag + (size_t)dir * PERDIR;
  const f16x8* Bxh = Bd;
  const f16x8* Bxl = Bd + KT*NT*64;
  const f16x8* Bhh = Bd + 2*KT*NT*64;
  const f16x8* Bhl = Bd + 3*KT*NT*64;
  const f32x4 zz = {0.f, 0.f, 0.f, 0.f};

  // hoisted bias chunk for x-staging (k = w*32 + l4*8 + e)
  int k8 = w*32 + (l4<<3);
  float bb[8];
#pragma unroll
  for (int e = 0; e < 8; ++e) bb[e] = 0.f;
  if (k8 + 8 <= Hc) {
    f32x4 a = *(const f32x4*)&bias[k8];
    f32x4 b = *(const f32x4*)&bias[k8+4];
#pragma unroll
    for (int e = 0; e < 4; ++e) { bb[e] = a[e]; bb[e+4] = b[e]; }
  } else if (k8 < Hc) {
    f32x4 a = *(const f32x4*)&bias[k8];
#pragma unroll
    for (int e = 0; e < 4; ++e) bb[e] = a[e];
  }

  // ---- h0: per-graph max-pool of raw node, lane-local (c, 4 graphs) ----
  float hreg[2][4];
#pragma unroll
  for (int qi = 0; qi < 2; ++qi) {
    int c = cq[qi];
#pragma unroll
    for (int j = 0; j < 4; ++j) {
      float m = 0.f;
      if (c < Hc) {
        m = -1e30f;
        int st = stj[j], sz = szj[j];
        for (int i = 0; i < sz; ++i)
          m = fmaxf(m, node[(size_t)(st + i) * Hc + c]);
      }
      hreg[qi][j] = m;
      afh_write(AfH[0], l15, (l4<<2)+j, c & ~1, f32_to_hl(m), lane);
    }
  }

#define HSTEP(S) { \
    constexpr int CUR = (S)&1; \
    constexpr int NXT = CUR^1; \
    f32x4 ha[2][3]; \
    _Pragma("unroll") \
    for (int qi = 0; qi < 2; ++qi) { ha[qi][0] = zz; ha[qi][1] = zz; ha[qi][2] = zz; } \
    _Pragma("unroll 2") \
    for (int kt = 0; kt < KT; ++kt) { \
      f16x8 ahh = *(const f16x8*)&AfH[CUR][0][kt][lane*4]; \
      f16x8 ahl = *(const f16x8*)&AfH[CUR][1][kt][lane*4]; \
      _Pragma("unroll") \
      for (int qi = 0; qi < 2; ++qi) { \
        _Pragma("unroll") \
        for (int sec = 0; sec < 3; ++sec) { \
          int nt = sec*NQ + qv[qi]; \
          f16x8 bh = Bhh[(kt*NT + nt)*64 + lane]; \
          f16x8 bl = Bhl[(kt*NT + nt)*64 + lane]; \
          ha[qi][sec] = MFMA16(ahh, bh, ha[qi][sec]); \
          ha[qi][sec] = MFMA16(ahh, bl, ha[qi][sec]); \
          ha[qi][sec] = MFMA16(ahl, bh, ha[qi][sec]); \
        } \
      } \
    } \
    int tt = 4*T + (S); \
    int time = dir ? (Ld-1-tt) : tt; \
    _Pragma("unroll") \
    for (int qi = 0; qi < 2; ++qi) { \
      int c = cq[qi]; \
      _Pragma("unroll") \
      for (int j = 0; j < 4; ++j) { \
        float rp_ = ha[qi][0][j] + xa[qi][0][S][j] + bcr[qi]; \
        float zp_ = ha[qi][1][j] + xa[qi][1][S][j] + bcz[qi]; \
        float r_ = 1.f/(1.f + __expf(-rp_)); \
        float z_ = 1.f/(1.f + __expf(-zp_)); \
        float n_ = tanhf(xa[qi][2][S][j] + bci[qi] + r_*(ha[qi][2][j] + bch[qi])); \
        float h_ = (1.f - z_)*n_ + z_*hreg[qi][j]; \
        if (c >= Hc) h_ = 0.f; \
        hreg[qi][j] = h_; \
        if (c < Hc && time < szj[j]) \
          out[(size_t)(1 + stj[j] + time)*600 + dir*Hc + c] = h_; \
        afh_write(AfH[NXT], l15, (l4<<2)+j, c & ~1, f32_to_hl(h_), lane); \
      } \
    } \
    __syncthreads(); \
  }

#pragma unroll 1
  for (int T = 0; T < Ld/4; ++T) {
    // ---- stage x A-fragments for 4 future steps (wave w covers kt = w) ----
#pragma unroll
    for (int s = 0; s < 4; ++s) {
      int tt = 4*T + s;
      int time = dir ? (Ld-1-tt) : tt;
      float xv[8];
#pragma unroll
      for (int e = 0; e < 8; ++e) xv[e] = 0.f;
      if (time < szG) {
        const float* rp = node + (size_t)(stG + time) * Hc + k8;
        if (k8 + 8 <= Hc) {
          f32x4 a = *(const f32x4*)rp;
          f32x4 b = *(const f32x4*)(rp + 4);
#pragma unroll
          for (int e = 0; e < 4; ++e) {
            xv[e]   = fmaxf(a[e] + bb[e],   0.f);
            xv[e+4] = fmaxf(b[e] + bb[e+4], 0.f);
          }
        } else if (k8 < Hc) {
          f32x4 a = *(const f32x4*)rp;
#pragma unroll
          for (int e = 0; e < 4; ++e) xv[e] = fmaxf(a[e] + bb[e], 0.f);
        }
      }
      f16x8 vh, vl;
#pragma unroll
      for (int e = 0; e < 8; ++e) {
        vh[e] = (_Float16)xv[e];
        vl[e] = (_Float16)(xv[e] - (float)vh[e]);
      }
      *(f16x8*)&AfX[0][s][w][lane*4] = vh;
      *(f16x8*)&AfX[1][s][w][lane*4] = vl;
    }
    __syncthreads();

    // ---- x-phase: 4 steps of input projection into persistent registers ----
    f32x4 xa[2][3][4];
#pragma unroll
    for (int qi = 0; qi < 2; ++qi)
#pragma unroll
      for (int sec = 0; sec < 3; ++sec)
#pragma unroll
        for (int mt = 0; mt < 4; ++mt) xa[qi][sec][mt] = zz;

#pragma unroll 1
    for (int kt = 0; kt < KT; ++kt) {
      f16x8 axh[4], axl[4];
#pragma unroll
      for (int mt = 0; mt < 4; ++mt) {
        axh[mt] = *(const f16x8*)&AfX[0][mt][kt][lane*4];
        axl[mt] = *(const f16x8*)&AfX[1][mt][kt][lane*4];
      }
#pragma unroll
      for (int qi = 0; qi < 2; ++qi) {
#pragma unroll
        for (int sec = 0; sec < 3; ++sec) {
          int nt = sec*NQ + qv[qi];
          f16x8 bh = Bxh[(kt*NT + nt)*64 + lane];
          f16x8 bl = Bxl[(kt*NT + nt)*64 + lane];
#pragma unroll
          for (int mt = 0; mt < 4; ++mt) {
            xa[qi][sec][mt] = MFMA16(axh[mt], bh, xa[qi][sec][mt]);
            xa[qi][sec][mt] = MFMA16(axh[mt], bl, xa[qi][sec][mt]);
            xa[qi][sec][mt] = MFMA16(axl[mt], bh, xa[qi][sec][mt]);
          }
        }
      }
    }

    // ---- 4 recurrent steps (1 barrier each) ----
    HSTEP(0)
    HSTEP(1)
    HSTEP(2)
    HSTEP(3)
  }
#undef HSTEP
}

extern "C" void kernel_launch(void* const* d_in, const int* in_sizes, int n_in,
                              void* d_out, int out_size, void* d_ws, size_t ws_size,
                              hipStream_t stream) {
  const float* node  = (const float*)d_in[0];
  const float* bias  = (const float*)d_in[1];
  const float* Wih_f = (const float*)d_in[2];
  const float* Whh_f = (const float*)d_in[3];
  const float* bih_f = (const float*)d_in[4];
  const float* bhh_f = (const float*)d_in[5];
  const float* Wih_b = (const float*)d_in[6];
  const float* Whh_b = (const float*)d_in[7];
  const float* bih_b = (const float*)d_in[8];
  const float* bhh_b = (const float*)d_in[9];
  const int* starts  = (const int*)d_in[10];
  const int* sizes   = (const int*)d_in[11];

  int ngr = in_sizes[10];          // 2048 graphs
  int ntile = ngr / GB;            // 128 tiles of 16 graphs

  float* out = (float*)d_out;
  f16x8* Bfrag = (f16x8*)d_ws;
  float* bcomb = (float*)((char*)d_ws + (size_t)TOTF*16);

  int prep_threads = TOTF + 2560 + 600;
  hipLaunchKernelGGL(k_prep, dim3((prep_threads + 255)/256), dim3(256), 0, stream,
                     Wih_f, Whh_f, Wih_b, Whh_b, bih_f, bhh_f, bih_b, bhh_b,
                     node, bias, Bfrag, bcomb, out);
  hipLaunchKernelGGL(k_rec, dim3(2*ntile), dim3(640), 0, stream,
                     node, bias, Bfrag, bcomb, starts, sizes, out);
}